// Round 4
// baseline (8419.115 us; speedup 1.0000x reference)
//
#include <hip/hip_runtime.h>
#include <hip/hip_fp16.h>
#include <math.h>

#define B_    32
#define TE    1024
#define TD    512
#define E_    512
#define F_    32
#define K_    31
#define KH    15
#define CHUNK 64
#define NCH   (TE / CHUNK)        // 16 chunks per batch row
#define NBLK  (B_ * NCH)          // 512 blocks = 2/CU x 256 CU, all resident

typedef __attribute__((ext_vector_type(8))) short short8;
typedef __attribute__((ext_vector_type(4))) float f32x4;

#define KKc   2.885390081777927f  // 2*log2(e)

__device__ __forceinline__ unsigned short f2bf(float x) {   // RNE f32->bf16
    unsigned u = __float_as_uint(x);
    unsigned r = (u + 0x7fffu + ((u >> 16) & 1u)) >> 16;
    return (unsigned short)r;
}
__device__ __forceinline__ float bf2f(unsigned short h) {
    return __uint_as_float(((unsigned)h) << 16);
}

// Agent-scope accessors: cross-XCD coherent without cache-wide invalidates.
__device__ __forceinline__ float gldf(const float* p) {
    return __hip_atomic_load(p, __ATOMIC_RELAXED, __HIP_MEMORY_SCOPE_AGENT);
}
__device__ __forceinline__ void gstf(float* p, float v) {
    __hip_atomic_store(p, v, __ATOMIC_RELAXED, __HIP_MEMORY_SCOPE_AGENT);
}

// ---------------------------------------------------------------------------
// Prologue: w_loc (F,U) -> transposed bf16 [u][c], PRE-SCALED by KK=2*log2(e)
// so the whole tanh argument arrives in exp2 domain. Zero-inits step flags.
// ---------------------------------------------------------------------------
__global__ void prep_kernel(const float* __restrict__ wloc,
                            unsigned short* __restrict__ WTh,
                            int* __restrict__ flags)
{
    const int u = threadIdx.x;                 // 512 threads
    #pragma unroll
    for (int c = 0; c < F_; ++c)
        WTh[u * F_ + c] = f2bf(KKc * wloc[c * 512 + u]);
    __hip_atomic_store(&flags[u], 0, __ATOMIC_RELAXED, __HIP_MEMORY_SCOPE_AGENT);
}

// ---------------------------------------------------------------------------
// Persistent kernel, 1024 threads (16 waves), 2 blocks/CU exact residency.
// enc tile lives in 16 VGPR/lane (f16, KK-prescaled); LDS ~17 KB.
// Epilogue math: e_t = V0 - 2*sum_u va*sigma; V0 const over t -> dropped
// (softmax shift invariance); p = exp2(-KK * red).
// Inter-step sync = per-batch flag barrier (16 blocks), agent-scope atomics,
// parity double-buffer (clobber analysis unchanged from round 2).
// ---------------------------------------------------------------------------
__global__ __launch_bounds__(1024, 8)
void persist_kernel(const float* __restrict__ enc,   // B,TE,E
                    const float* __restrict__ dec,   // B,TD,E
                    const float* __restrict__ cw,    // K,1,F
                    const float* __restrict__ cb,    // F
                    const unsigned short* __restrict__ WTh, // U,F bf16 (KK*W)
                    const float* __restrict__ va,    // U
                    const float* __restrict__ ba,    // U
                    float* __restrict__ prG,         // 2,B,TE   exp(e)
                    float* __restrict__ paG,         // 2,B,TE   cum align
                    float* __restrict__ PsG,         // 2,B,NCH  partial sums
                    float* __restrict__ eout,        // B,TD,TE
                    int*   __restrict__ flags)       // B,NCH  steps completed
{
    __shared__ __align__(16) unsigned short fThS[CHUNK * F_]; // A-frag hi [t][c]
    __shared__ __align__(16) unsigned short fTlS[CHUNK * F_]; // A-frag lo
    __shared__ float cwS[K_ * F_];
    __shared__ float paW[CHUNK + 2 * KH + 4];                 // 98
    __shared__ float redT[CHUNK][17];                         // [t][wave], pad
    __shared__ float prS[CHUNK];                              // own exp(e), s-1
    __shared__ float paS[CHUNK];                              // own cum align

    const int tid   = threadIdx.x;
    const int g     = tid & 63;
    const int w     = tid >> 6;               // wave 0..15
    const int q     = g >> 4;                 // quad 0..3
    const int n16   = g & 15;
    const int b     = blockIdx.x >> 4;
    const int chunk = blockIdx.x & 15;
    const int t0    = chunk * CHUNK;
    const float NKK = -KKc;

    // ---- hoisted per-session state ----
    short8 bh[2];
    float vv[2], kba[2];
    #pragma unroll
    for (int ut = 0; ut < 2; ++ut) {
        const int u = w * 32 + ut * 16 + n16;
        bh[ut]  = ((const short8*)WTh)[u * 4 + q];
        vv[ut]  = va[u];
        kba[ut] = KKc * ba[u];
    }
    for (int i = tid; i < K_ * F_; i += 1024) cwS[i] = cw[i];
    const float cbR = cb[tid & 31];

    // ---- enc tile -> registers: lane's 32 fixed (t,u) elems, f16, KK-scaled
    __half2 er[4][2][2];
    #pragma unroll
    for (int tt = 0; tt < 4; ++tt)
        #pragma unroll
        for (int ut = 0; ut < 2; ++ut) {
            const int u = w * 32 + ut * 16 + n16;
            #pragma unroll
            for (int rp = 0; rp < 2; ++rp) {
                const int t = t0 + tt * 16 + q * 4 + rp * 2;
                float x0 = KKc * enc[((size_t)b * TE + t) * E_ + u];
                float x1 = KKc * enc[((size_t)b * TE + t + 1) * E_ + u];
                er[tt][ut][rp] = __halves2half2(__float2half_rn(x0),
                                                __float2half_rn(x1));
            }
        }

    int* myf = flags + b * NCH;
    const size_t rowB = (size_t)b * TE + t0;

    for (int s = 0; s < TD; ++s) {
        const int rp = (s + 1) & 1;           // parity of step s-1 buffers
        const int wp = s & 1;                 // parity of step s buffers

        // prefetch query row (KK-scaled, +KK*ba) before the sync
        const float* qrow = dec + ((size_t)b * TD + s) * E_;
        float qb[2];
        #pragma unroll
        for (int ut = 0; ut < 2; ++ut)
            qb[ut] = fmaf(KKc, qrow[w * 32 + ut * 16 + n16], kba[ut]);

        if (s == 0) {
            if (tid < CHUNK + 2 * KH + 4) paW[tid] = 0.0f;
            if (tid < CHUNK) {
                paS[tid] = 0.0f;
                gstf(&paG[wp * (B_ * TE) + rowB + tid], 0.0f);
            }
        } else {
            // ---- per-batch barrier: all 16 chunks finished step s-1 ----
            if (tid < NCH) {
                while (__hip_atomic_load(&myf[tid], __ATOMIC_RELAXED,
                                         __HIP_MEMORY_SCOPE_AGENT) < s)
                    __builtin_amdgcn_s_sleep(1);
            }
            __syncthreads();

            if (w < 2) {   // only waves 0-1 need inv (phase-1 writers)
                float S = 0.0f;
                if (g < 16) S = gldf(&PsG[rp * (B_ * NCH) + b * NCH + g]);
                S += __shfl_xor(S, 1); S += __shfl_xor(S, 2);
                S += __shfl_xor(S, 4); S += __shfl_xor(S, 8);
                S = __shfl(S, 0);
                const float inv = 1.0f / S;

                if (tid < CHUNK) {
                    // own chunk: finish softmax s-1, update cum align, publish
                    float pn  = prS[tid] * inv;
                    float pan = paS[tid] + pn;
                    paS[tid]      = pan;
                    paW[KH + tid] = pan;
                    eout[((size_t)b * TD + (s - 1)) * TE + t0 + tid] = pn;
                    gstf(&paG[wp * (B_ * TE) + rowB + tid], pan);
                } else if (tid < CHUNK + 2 * KH) {
                    // halo from neighbors (published step s-1 data)
                    int hh = tid - CHUNK;                   // 0..29
                    int t  = (hh < KH) ? (t0 - KH + hh)
                                       : (t0 + CHUNK + (hh - KH));
                    int wi = (hh < KH) ? hh : (CHUNK + hh);
                    float v = 0.0f;
                    if (t >= 0 && t < TE) {
                        size_t off = (size_t)rp * (B_ * TE) + (size_t)b * TE + t;
                        v = gldf(&paG[off]) + gldf(&prG[off]) * inv;
                    }
                    paW[wi] = v;
                } else if (tid < CHUNK + 2 * KH + 4) {
                    paW[tid] = 0.0f;                        // pad 94..97
                }
            }
        }
        __syncthreads();

        // ---- conv -> fT bf16 hi/lo, A-operand layout [t][c]; 2 t/thread ----
        {
            const int c    = tid & 31;
            const int ts   = tid >> 5;        // 0..31
            const int base = ts * 2;
            float a0 = cbR, a1 = cbR;
            #pragma unroll
            for (int k = 0; k < K_; ++k) {
                float wv = cwS[k * F_ + c];
                a0 = fmaf(wv, paW[base + k],     a0);
                a1 = fmaf(wv, paW[base + k + 1], a1);
            }
            unsigned short h0 = f2bf(a0), h1 = f2bf(a1);
            fThS[(base + 0) * F_ + c] = h0;
            fTlS[(base + 0) * F_ + c] = f2bf(a0 - bf2f(h0));
            fThS[(base + 1) * F_ + c] = h1;
            fTlS[(base + 1) * F_ + c] = f2bf(a1 - bf2f(h1));
        }
        __syncthreads();

        // ---- MFMA + fused epilogue.  acc = KK*(loc + enc + q + ba) ----
        const short8* AH = (const short8*)fThS;
        const short8* AL = (const short8*)fTlS;
        #pragma unroll
        for (int tt = 0; tt < 4; ++tt) {
            short8 ah = AH[(tt * 16 + n16) * 4 + q];
            short8 al = AL[(tt * 16 + n16) * 4 + q];
            float sacc[4] = {0.0f, 0.0f, 0.0f, 0.0f};
            #pragma unroll
            for (int ut = 0; ut < 2; ++ut) {
                float2 e01 = __half22float2(er[tt][ut][0]);
                float2 e23 = __half22float2(er[tt][ut][1]);
                f32x4 acc = (f32x4){qb[ut] + e01.x, qb[ut] + e01.y,
                                    qb[ut] + e23.x, qb[ut] + e23.y};
                acc = __builtin_amdgcn_mfma_f32_16x16x32_bf16(ah, bh[ut], acc, 0, 0, 0);
                acc = __builtin_amdgcn_mfma_f32_16x16x32_bf16(al, bh[ut], acc, 0, 0, 0);
                #pragma unroll
                for (int r = 0; r < 4; ++r) {
                    float rr = __builtin_amdgcn_exp2f(acc[r]);      // e^{2x}
                    sacc[r] = fmaf(vv[ut],
                                   __builtin_amdgcn_rcpf(rr + 1.0f), sacc[r]);
                }
            }
            #pragma unroll
            for (int r = 0; r < 4; ++r) {
                float sa = sacc[r];
                sa += __shfl_xor(sa, 1);
                sa += __shfl_xor(sa, 2);
                sa += __shfl_xor(sa, 4);
                sa += __shfl_xor(sa, 8);
                if (n16 == 0) redT[tt * 16 + q * 4 + r][w] = sa;
            }
        }
        __syncthreads();

        // ---- final: sum 16 wave-partials, p = exp2(-KK*red), publish ----
        if (tid < CHUNK) {
            float red = 0.0f;
            #pragma unroll
            for (int k = 0; k < 16; ++k) red += redT[tid][k];
            // |red| <= sum|va| <= 25.6 -> exp2 arg <= 74, safe in f32
            float p = __builtin_amdgcn_exp2f(red * NKK);
            prS[tid] = p;
            gstf(&prG[wp * (B_ * TE) + rowB + tid], p);
            float sp = p;
            #pragma unroll
            for (int off = 32; off; off >>= 1) sp += __shfl_xor(sp, off);
            if (tid == 0) {
                gstf(&PsG[wp * (B_ * NCH) + b * NCH + chunk], sp);
                asm volatile("s_waitcnt vmcnt(0)" ::: "memory");
                __hip_atomic_store(&myf[chunk], s + 1, __ATOMIC_RELAXED,
                                   __HIP_MEMORY_SCOPE_AGENT);
            }
        }
        // no trailing barrier: next iter's post-wait __syncthreads orders
        // waves 1..15 behind wave 0; redT/prS hazards covered by >=2 barriers.
    }

    // ---- tail: normalize last step (parity (TD-1)&1 == 1) into eout ----
    if (tid < NCH) {
        while (__hip_atomic_load(&myf[tid], __ATOMIC_RELAXED,
                                 __HIP_MEMORY_SCOPE_AGENT) < TD)
            __builtin_amdgcn_s_sleep(1);
    }
    __syncthreads();
    if (tid < CHUNK) {
        float S = 0.0f;
        if (g < 16) S = gldf(&PsG[1 * (B_ * NCH) + b * NCH + g]);
        S += __shfl_xor(S, 1); S += __shfl_xor(S, 2);
        S += __shfl_xor(S, 4); S += __shfl_xor(S, 8);
        S = __shfl(S, 0);
        float pn = prS[tid] * (1.0f / S);
        eout[((size_t)b * TD + (TD - 1)) * TE + t0 + tid] = pn;
    }
}

// ---------------------------------------------------------------------------
// Context matmul: c[b,d,e] = sum_t eo[b,d,t] * enc[b,t,e]
// ---------------------------------------------------------------------------
__global__ __launch_bounds__(256)
void context_kernel(const float* __restrict__ eo,   // B,TD,TE
                    const float* __restrict__ enc,  // B,TE,E
                    float* __restrict__ cout)       // B,TD,E
{
    __shared__ float eoT[64][36];
    const int b = blockIdx.y, d0 = blockIdx.x * 32, tid = threadIdx.x;

    float2 acc[32];
    #pragma unroll
    for (int d = 0; d < 32; ++d) { acc[d].x = 0.0f; acc[d].y = 0.0f; }

    for (int tc = 0; tc < TE / 64; ++tc) {
        __syncthreads();
        #pragma unroll
        for (int r = 0; r < 8; ++r) {
            int lin = r * 256 + tid;
            int d = lin >> 6, t = lin & 63;
            eoT[t][d] = eo[((size_t)b * TD + d0 + d) * TE + tc * 64 + t];
        }
        __syncthreads();
        #pragma unroll 4
        for (int t = 0; t < 64; ++t) {
            float2 ev = *(const float2*)&enc[((size_t)b * TE + tc * 64 + t) * E_ + 2 * tid];
            #pragma unroll
            for (int dq = 0; dq < 8; ++dq) {
                float4 wv = *(const float4*)&eoT[t][dq * 4];
                acc[dq * 4 + 0].x += wv.x * ev.x; acc[dq * 4 + 0].y += wv.x * ev.y;
                acc[dq * 4 + 1].x += wv.y * ev.x; acc[dq * 4 + 1].y += wv.y * ev.y;
                acc[dq * 4 + 2].x += wv.z * ev.x; acc[dq * 4 + 2].y += wv.z * ev.y;
                acc[dq * 4 + 3].x += wv.w * ev.x; acc[dq * 4 + 3].y += wv.w * ev.y;
            }
        }
    }
    #pragma unroll
    for (int d = 0; d < 32; ++d)
        *(float2*)&cout[((size_t)b * TD + d0 + d) * E_ + 2 * tid] = acc[d];
}

// ---------------------------------------------------------------------------
extern "C" void kernel_launch(void* const* d_in, const int* in_sizes, int n_in,
                              void* d_out, int out_size, void* d_ws, size_t ws_size,
                              hipStream_t stream) {
    const float* enc  = (const float*)d_in[0];
    const float* dec  = (const float*)d_in[1];
    const float* cw   = (const float*)d_in[2];
    const float* cb   = (const float*)d_in[3];
    const float* wloc = (const float*)d_in[4];
    const float* va   = (const float*)d_in[5];
    const float* ba   = (const float*)d_in[6];

    float* c_out = (float*)d_out;                          // B*TD*E
    float* e_out = (float*)d_out + (size_t)B_ * TD * E_;   // B*TD*TE

    float* ws  = (float*)d_ws;
    float* prG = ws;                                       // 2*B*TE
    float* paG = ws + 2 * (size_t)B_ * TE;                 // 2*B*TE
    float* PsG = ws + 4 * (size_t)B_ * TE;                 // 2*B*NCH
    unsigned short* WTh = (unsigned short*)(PsG + 2 * (size_t)B_ * NCH);
    int* flags = (int*)(WTh + 512 * F_);                   // B*NCH ints

    prep_kernel<<<1, 512, 0, stream>>>(wloc, WTh, flags);

    persist_kernel<<<NBLK, 1024, 0, stream>>>(
        enc, dec, cw, cb, WTh, va, ba,
        prG, paG, PsG, e_out, flags);

    context_kernel<<<dim3(TD / 32, B_), 256, 0, stream>>>(e_out, enc, c_out);
}